// Round 5
// baseline (1007.862 us; speedup 1.0000x reference)
//
#include <hip/hip_runtime.h>

#define DIM 64
#define BBITS 3             // 8 buckets per bin
#define BPB (1 << BBITS)
#define NGROUP 8            // cursor replication: one segment per blockIdx%8 (~XCD)

// ---------------- fallback (round-1) atomic kernel ----------------
__global__ void coo_scatter_kernel(const float* __restrict__ user_emb,
                                   const float* __restrict__ entity_emb,
                                   const int* __restrict__ rows,
                                   const int* __restrict__ cols,
                                   const float* __restrict__ vals,
                                   float* __restrict__ entity_agg,
                                   float* __restrict__ user_agg,
                                   int nnz) {
    long long tid = (long long)blockIdx.x * blockDim.x + threadIdx.x;
    long long total = (long long)nnz * DIM;
    if (tid >= total) return;
    int edge = (int)(tid >> 6);
    int d = (int)(tid & 63);
    int r = rows[edge];
    int c = cols[edge];
    float v = vals[edge];
    atomicAdd(&entity_agg[c * DIM + d], v * user_emb[r * DIM + d]);
    atomicAdd(&user_agg[r * DIM + d], v * entity_emb[c * DIM + d]);
}

// ---------------- binned gather path ----------------
// bucket space: [0, ne) entity rows, [ne, ne+nu) user rows. bin = bucket >> 3.
// Segments ordered bin-major: seg(bin, g) = bin*NGROUP + g, so bin b's records
// are contiguous: [offs[b*NGROUP], offs[(b+1)*NGROUP]).
// record: uint2 { meta, valbits }; meta = (local<<18) | (side<<17) | src

__global__ void count_bins(const int* __restrict__ rows,
                           const int* __restrict__ cols,
                           int* __restrict__ cnt, int ne, int nnz) {
    int i = blockIdx.x * blockDim.x + threadIdx.x;
    if (i >= nnz) return;
    int g = blockIdx.x & (NGROUP - 1);
    atomicAdd(&cnt[(cols[i] >> BBITS) * NGROUP + g], 1);
    atomicAdd(&cnt[((ne + rows[i]) >> BBITS) * NGROUP + g], 1);
}

__global__ void scan_kernel(const int* __restrict__ cnt,
                            int* __restrict__ offs,
                            int* __restrict__ cursor, int n) {
    __shared__ int partial[1024];
    int t = threadIdx.x;
    int chunk = (n + 1023) / 1024;
    int s = t * chunk;
    int e = s + chunk; if (e > n) e = n;
    int sum = 0;
    for (int i = s; i < e; ++i) sum += cnt[i];
    partial[t] = sum;
    __syncthreads();
    if (t == 0) {
        int run = 0;
        for (int i = 0; i < 1024; ++i) { int v = partial[i]; partial[i] = run; run += v; }
        offs[n] = run;   // == 2*nnz
    }
    __syncthreads();
    int off = partial[t];
    for (int i = s; i < e; ++i) {
        offs[i] = off;
        cursor[i] = off;
        off += cnt[i];
    }
}

__global__ void fill_bins(const int* __restrict__ rows,
                          const int* __restrict__ cols,
                          const float* __restrict__ vals,
                          int* __restrict__ cursor,
                          uint2* __restrict__ payload, int ne, int nnz) {
    int i = blockIdx.x * blockDim.x + threadIdx.x;
    if (i >= nnz) return;
    int g = blockIdx.x & (NGROUP - 1);
    int r = rows[i], c = cols[i];
    unsigned vb = __float_as_uint(vals[i]);
    // entity side: bucket = c, src = r, side 0
    unsigned local1 = (unsigned)(c & (BPB - 1));
    int s1 = atomicAdd(&cursor[(c >> BBITS) * NGROUP + g], 1);
    payload[s1] = make_uint2((local1 << 18) | (unsigned)r, vb);
    // user side: bucket = ne + r, src = c, side 1
    int b2 = ne + r;
    unsigned local2 = (unsigned)(b2 & (BPB - 1));
    int s2 = atomicAdd(&cursor[(b2 >> BBITS) * NGROUP + g], 1);
    payload[s2] = make_uint2((local2 << 18) | (1u << 17) | (unsigned)c, vb);
}

// one WAVE per bin: 8 register accumulators x 64 lanes (lane = dim).
__global__ __launch_bounds__(256) void agg_bins(const float* __restrict__ user_emb,
                                                const float* __restrict__ entity_emb,
                                                const int* __restrict__ offs,
                                                const uint2* __restrict__ payload,
                                                float* __restrict__ out,
                                                int nbins) {
    int wave = blockIdx.x * 4 + (threadIdx.x >> 6);
    int lane = threadIdx.x & 63;
    if (wave >= nbins) return;
    int beg = offs[wave * NGROUP];
    int end = offs[wave * NGROUP + NGROUP];

    float acc[BPB];
#pragma unroll
    for (int k = 0; k < BPB; ++k) acc[k] = 0.f;

    int i = beg;
    for (; i + 4 <= end; i += 4) {
        uint2 r0 = payload[i + 0];
        uint2 r1 = payload[i + 1];
        uint2 r2 = payload[i + 2];
        uint2 r3 = payload[i + 3];
        const float* __restrict__ t0 = (r0.x & (1u << 17)) ? entity_emb : user_emb;
        const float* __restrict__ t1 = (r1.x & (1u << 17)) ? entity_emb : user_emb;
        const float* __restrict__ t2 = (r2.x & (1u << 17)) ? entity_emb : user_emb;
        const float* __restrict__ t3 = (r3.x & (1u << 17)) ? entity_emb : user_emb;
        float e0 = t0[(size_t)(r0.x & 0x1FFFFu) * DIM + lane];
        float e1 = t1[(size_t)(r1.x & 0x1FFFFu) * DIM + lane];
        float e2 = t2[(size_t)(r2.x & 0x1FFFFu) * DIM + lane];
        float e3 = t3[(size_t)(r3.x & 0x1FFFFu) * DIM + lane];
        float m0 = __uint_as_float(r0.y) * e0;
        float m1 = __uint_as_float(r1.y) * e1;
        float m2 = __uint_as_float(r2.y) * e2;
        float m3 = __uint_as_float(r3.y) * e3;
        unsigned l0 = r0.x >> 18, l1 = r1.x >> 18, l2 = r2.x >> 18, l3 = r3.x >> 18;
#pragma unroll
        for (int k = 0; k < BPB; ++k) {
            acc[k] += (l0 == (unsigned)k) ? m0 : 0.f;
            acc[k] += (l1 == (unsigned)k) ? m1 : 0.f;
            acc[k] += (l2 == (unsigned)k) ? m2 : 0.f;
            acc[k] += (l3 == (unsigned)k) ? m3 : 0.f;
        }
    }
    for (; i < end; ++i) {
        uint2 r = payload[i];
        const float* __restrict__ t = (r.x & (1u << 17)) ? entity_emb : user_emb;
        float m = __uint_as_float(r.y) * t[(size_t)(r.x & 0x1FFFFu) * DIM + lane];
        unsigned l = r.x >> 18;
#pragma unroll
        for (int k = 0; k < BPB; ++k) acc[k] += (l == (unsigned)k) ? m : 0.f;
    }

    // buckets [wave*8, wave*8+8) -> contiguous out rows; coalesced stores.
    long long base = (long long)wave * (BPB * DIM) + lane;
#pragma unroll
    for (int k = 0; k < BPB; ++k) out[base + (long long)k * DIM] = acc[k];
}

extern "C" void kernel_launch(void* const* d_in, const int* in_sizes, int n_in,
                              void* d_out, int out_size, void* d_ws, size_t ws_size,
                              hipStream_t stream) {
    const float* user_emb   = (const float*)d_in[0];  // [n_users, 64]
    const float* entity_emb = (const float*)d_in[1];  // [n_entities, 64]
    const int*   rows       = (const int*)d_in[2];
    const int*   cols       = (const int*)d_in[3];
    const float* vals       = (const float*)d_in[4];
    int nnz = in_sizes[2];
    int nu  = in_sizes[0] / DIM;   // 100000
    int ne  = in_sizes[1] / DIM;   // 50000
    int nb  = ne + nu;             // 150000 buckets
    int nbins = (nb + BPB - 1) >> BBITS;   // 18750
    int nseg  = nbins * NGROUP;            // 150000 segments

    float* out = (float*)d_out;

    // ws layout (ints): cnt[nseg] | cursor[nseg] | offs[nseg+1] | pad | payload[2*nnz] uint2
    size_t n_ints = (size_t)nseg * 3 + 1;
    size_t pay_off_ints = (n_ints + 1) & ~(size_t)1;
    size_t need = pay_off_ints * 4 + (size_t)2 * nnz * 8;

    if (ws_size < need || (ne & (BPB - 1)) != 0) {
        float* entity_agg = out;
        float* user_agg   = out + (size_t)ne * DIM;
        hipMemsetAsync(d_out, 0, (size_t)out_size * sizeof(float), stream);
        long long total = (long long)nnz * DIM;
        int block = 256;
        long long grid = (total + block - 1) / block;
        coo_scatter_kernel<<<(int)grid, block, 0, stream>>>(
            user_emb, entity_emb, rows, cols, vals, entity_agg, user_agg, nnz);
        return;
    }

    int*   cnt     = (int*)d_ws;
    int*   cursor  = cnt + nseg;
    int*   offs    = cursor + nseg;             // nseg+1 entries
    uint2* payload = (uint2*)((int*)d_ws + pay_off_ints);

    hipMemsetAsync(cnt, 0, (size_t)nseg * sizeof(int), stream);

    int block = 256;
    int gEdges = (nnz + block - 1) / block;
    count_bins<<<gEdges, block, 0, stream>>>(rows, cols, cnt, ne, nnz);
    scan_kernel<<<1, 1024, 0, stream>>>(cnt, offs, cursor, nseg);
    fill_bins<<<gEdges, block, 0, stream>>>(rows, cols, vals, cursor, payload, ne, nnz);

    int gAgg = (nbins + 3) / 4;   // 4 waves (bins) per block
    agg_bins<<<gAgg, block, 0, stream>>>(user_emb, entity_emb, offs, payload, out, nbins);
}

// Round 6
// 679.389 us; speedup vs baseline: 1.4835x; 1.4835x over previous
//
#include <hip/hip_runtime.h>

#define DIM 64
#define BBITS 3             // 8 buckets per bin
#define BPB (1 << BBITS)
#define NGROUP 8            // cursor replication: one segment per blockIdx%8 (~XCD)
#define SCHUNK 2048         // elements per scan block (256 threads x 8)

// ---------------- fallback (round-1) atomic kernel ----------------
__global__ void coo_scatter_kernel(const float* __restrict__ user_emb,
                                   const float* __restrict__ entity_emb,
                                   const int* __restrict__ rows,
                                   const int* __restrict__ cols,
                                   const float* __restrict__ vals,
                                   float* __restrict__ entity_agg,
                                   float* __restrict__ user_agg,
                                   int nnz) {
    long long tid = (long long)blockIdx.x * blockDim.x + threadIdx.x;
    long long total = (long long)nnz * DIM;
    if (tid >= total) return;
    int edge = (int)(tid >> 6);
    int d = (int)(tid & 63);
    int r = rows[edge];
    int c = cols[edge];
    float v = vals[edge];
    atomicAdd(&entity_agg[c * DIM + d], v * user_emb[r * DIM + d]);
    atomicAdd(&user_agg[r * DIM + d], v * entity_emb[c * DIM + d]);
}

// ---------------- binned gather path ----------------
// bucket space: [0, ne) entity rows, [ne, ne+nu) user rows. bin = bucket >> 3.
// Segments bin-major: seg(bin,g) = bin*NGROUP + g; bin b's records are
// contiguous: [offs[b*NGROUP], offs[(b+1)*NGROUP]).
// record: uint2 { meta, valbits }; meta = (local<<18) | (side<<17) | src

__global__ void count_bins(const int* __restrict__ rows,
                           const int* __restrict__ cols,
                           int* __restrict__ cnt, int ne, int nnz) {
    int i = blockIdx.x * blockDim.x + threadIdx.x;
    if (i >= nnz) return;
    int g = blockIdx.x & (NGROUP - 1);
    atomicAdd(&cnt[(cols[i] >> BBITS) * NGROUP + g], 1);
    atomicAdd(&cnt[((ne + rows[i]) >> BBITS) * NGROUP + g], 1);
}

// ---- hierarchical scan: block sums -> scan sums -> apply ----
__global__ __launch_bounds__(256) void scan_block_sums(const int* __restrict__ cnt,
                                                       int* __restrict__ bsum, int n) {
    __shared__ int sh[256];
    int b = blockIdx.x, t = threadIdx.x;
    int base = b * SCHUNK + t * 8;
    int s = 0;
#pragma unroll
    for (int j = 0; j < 8; ++j) {
        int i = base + j;
        if (i < n) s += cnt[i];
    }
    sh[t] = s;
    __syncthreads();
    for (int off = 128; off > 0; off >>= 1) {
        if (t < off) sh[t] += sh[t + off];
        __syncthreads();
    }
    if (t == 0) bsum[b] = sh[0];
}

__global__ void scan_bsums(const int* __restrict__ bsum,
                           int* __restrict__ bpre,
                           int* __restrict__ total_out, int nblk) {
    if (threadIdx.x == 0 && blockIdx.x == 0) {
        int run = 0;
        for (int i = 0; i < nblk; ++i) { bpre[i] = run; run += bsum[i]; }
        *total_out = run;    // offs[n] == 2*nnz
    }
}

__global__ __launch_bounds__(256) void scan_apply(const int* __restrict__ cnt,
                                                  const int* __restrict__ bpre,
                                                  int* __restrict__ offs,
                                                  int* __restrict__ cursor, int n) {
    __shared__ int sh[256];
    int b = blockIdx.x, t = threadIdx.x;
    int base = b * SCHUNK + t * 8;
    int local[8];
    int s = 0;
#pragma unroll
    for (int j = 0; j < 8; ++j) {
        int i = base + j;
        local[j] = (i < n) ? cnt[i] : 0;
        s += local[j];
    }
    sh[t] = s;
    // inclusive Hillis-Steele over 256 thread sums
    for (int off = 1; off < 256; off <<= 1) {
        __syncthreads();
        int tmp = (t >= off) ? sh[t - off] : 0;
        __syncthreads();
        sh[t] += tmp;
    }
    __syncthreads();
    int run = bpre[b] + sh[t] - s;   // exclusive prefix for this thread's chunk
#pragma unroll
    for (int j = 0; j < 8; ++j) {
        int i = base + j;
        if (i < n) {
            offs[i] = run;
            cursor[i] = run;
            run += local[j];
        }
    }
}

__global__ void fill_bins(const int* __restrict__ rows,
                          const int* __restrict__ cols,
                          const float* __restrict__ vals,
                          int* __restrict__ cursor,
                          uint2* __restrict__ payload, int ne, int nnz) {
    int i = blockIdx.x * blockDim.x + threadIdx.x;
    if (i >= nnz) return;
    int g = blockIdx.x & (NGROUP - 1);
    int r = rows[i], c = cols[i];
    unsigned vb = __float_as_uint(vals[i]);
    unsigned local1 = (unsigned)(c & (BPB - 1));
    int s1 = atomicAdd(&cursor[(c >> BBITS) * NGROUP + g], 1);
    payload[s1] = make_uint2((local1 << 18) | (unsigned)r, vb);
    int b2 = ne + r;
    unsigned local2 = (unsigned)(b2 & (BPB - 1));
    int s2 = atomicAdd(&cursor[(b2 >> BBITS) * NGROUP + g], 1);
    payload[s2] = make_uint2((local2 << 18) | (1u << 17) | (unsigned)c, vb);
}

// one WAVE per bin: 8 register accumulators x 64 lanes (lane = dim).
__global__ __launch_bounds__(256) void agg_bins(const float* __restrict__ user_emb,
                                                const float* __restrict__ entity_emb,
                                                const int* __restrict__ offs,
                                                const uint2* __restrict__ payload,
                                                float* __restrict__ out,
                                                int nbins) {
    int wave = blockIdx.x * 4 + (threadIdx.x >> 6);
    int lane = threadIdx.x & 63;
    if (wave >= nbins) return;
    int beg = offs[wave * NGROUP];
    int end = offs[wave * NGROUP + NGROUP];

    float acc[BPB];
#pragma unroll
    for (int k = 0; k < BPB; ++k) acc[k] = 0.f;

    int i = beg;
    for (; i + 4 <= end; i += 4) {
        uint2 r0 = payload[i + 0];
        uint2 r1 = payload[i + 1];
        uint2 r2 = payload[i + 2];
        uint2 r3 = payload[i + 3];
        const float* __restrict__ t0 = (r0.x & (1u << 17)) ? entity_emb : user_emb;
        const float* __restrict__ t1 = (r1.x & (1u << 17)) ? entity_emb : user_emb;
        const float* __restrict__ t2 = (r2.x & (1u << 17)) ? entity_emb : user_emb;
        const float* __restrict__ t3 = (r3.x & (1u << 17)) ? entity_emb : user_emb;
        float e0 = t0[(size_t)(r0.x & 0x1FFFFu) * DIM + lane];
        float e1 = t1[(size_t)(r1.x & 0x1FFFFu) * DIM + lane];
        float e2 = t2[(size_t)(r2.x & 0x1FFFFu) * DIM + lane];
        float e3 = t3[(size_t)(r3.x & 0x1FFFFu) * DIM + lane];
        float m0 = __uint_as_float(r0.y) * e0;
        float m1 = __uint_as_float(r1.y) * e1;
        float m2 = __uint_as_float(r2.y) * e2;
        float m3 = __uint_as_float(r3.y) * e3;
        unsigned l0 = r0.x >> 18, l1 = r1.x >> 18, l2 = r2.x >> 18, l3 = r3.x >> 18;
#pragma unroll
        for (int k = 0; k < BPB; ++k) {
            acc[k] += (l0 == (unsigned)k) ? m0 : 0.f;
            acc[k] += (l1 == (unsigned)k) ? m1 : 0.f;
            acc[k] += (l2 == (unsigned)k) ? m2 : 0.f;
            acc[k] += (l3 == (unsigned)k) ? m3 : 0.f;
        }
    }
    for (; i < end; ++i) {
        uint2 r = payload[i];
        const float* __restrict__ t = (r.x & (1u << 17)) ? entity_emb : user_emb;
        float m = __uint_as_float(r.y) * t[(size_t)(r.x & 0x1FFFFu) * DIM + lane];
        unsigned l = r.x >> 18;
#pragma unroll
        for (int k = 0; k < BPB; ++k) acc[k] += (l == (unsigned)k) ? m : 0.f;
    }

    long long base = (long long)wave * (BPB * DIM) + lane;
#pragma unroll
    for (int k = 0; k < BPB; ++k) out[base + (long long)k * DIM] = acc[k];
}

extern "C" void kernel_launch(void* const* d_in, const int* in_sizes, int n_in,
                              void* d_out, int out_size, void* d_ws, size_t ws_size,
                              hipStream_t stream) {
    const float* user_emb   = (const float*)d_in[0];  // [n_users, 64]
    const float* entity_emb = (const float*)d_in[1];  // [n_entities, 64]
    const int*   rows       = (const int*)d_in[2];
    const int*   cols       = (const int*)d_in[3];
    const float* vals       = (const float*)d_in[4];
    int nnz = in_sizes[2];
    int nu  = in_sizes[0] / DIM;   // 100000
    int ne  = in_sizes[1] / DIM;   // 50000
    int nb  = ne + nu;             // 150000 buckets
    int nbins = (nb + BPB - 1) >> BBITS;   // 18750
    int nseg  = nbins * NGROUP;            // 150000 segments
    int nblk  = (nseg + SCHUNK - 1) / SCHUNK;  // 74 scan blocks

    float* out = (float*)d_out;

    // ws (ints): cnt[nseg] | cursor[nseg] | offs[nseg+1] | bsum[nblk] | bpre[nblk] | pad | payload
    size_t n_ints = (size_t)nseg * 3 + 1 + (size_t)nblk * 2;
    size_t pay_off_ints = (n_ints + 1) & ~(size_t)1;
    size_t need = pay_off_ints * 4 + (size_t)2 * nnz * 8;

    if (ws_size < need || (ne & (BPB - 1)) != 0) {
        float* entity_agg = out;
        float* user_agg   = out + (size_t)ne * DIM;
        hipMemsetAsync(d_out, 0, (size_t)out_size * sizeof(float), stream);
        long long total = (long long)nnz * DIM;
        int block = 256;
        long long grid = (total + block - 1) / block;
        coo_scatter_kernel<<<(int)grid, block, 0, stream>>>(
            user_emb, entity_emb, rows, cols, vals, entity_agg, user_agg, nnz);
        return;
    }

    int*   cnt     = (int*)d_ws;
    int*   cursor  = cnt + nseg;
    int*   offs    = cursor + nseg;             // nseg+1 entries
    int*   bsum    = offs + nseg + 1;
    int*   bpre    = bsum + nblk;
    uint2* payload = (uint2*)((int*)d_ws + pay_off_ints);

    hipMemsetAsync(cnt, 0, (size_t)nseg * sizeof(int), stream);

    int block = 256;
    int gEdges = (nnz + block - 1) / block;
    count_bins<<<gEdges, block, 0, stream>>>(rows, cols, cnt, ne, nnz);
    scan_block_sums<<<nblk, 256, 0, stream>>>(cnt, bsum, nseg);
    scan_bsums<<<1, 64, 0, stream>>>(bsum, bpre, offs + nseg, nblk);
    scan_apply<<<nblk, 256, 0, stream>>>(cnt, bpre, offs, cursor, nseg);
    fill_bins<<<gEdges, block, 0, stream>>>(rows, cols, vals, cursor, payload, ne, nnz);

    int gAgg = (nbins + 3) / 4;   // 4 waves (bins) per block
    agg_bins<<<gAgg, block, 0, stream>>>(user_emb, entity_emb, offs, payload, out, nbins);
}